// Round 6
// baseline (361.409 us; speedup 1.0000x reference)
//
#include <hip/hip_runtime.h>
#include <math.h>

namespace {
constexpr int kB = 256;
constexpr int kD = 128;
constexpr int kN = 500000;
constexpr int kKC = 2049;             // K + 1
constexpr int kNPair = kB * kKC;      // 524544
constexpr float kTInv = 1.0f / 0.07f;
constexpr float kMom = 0.5f;
constexpr int kRB = 256;              // reduction grid size
constexpr long long kM = (long long)kN * kD;    // 64,000,000 floats per bank
constexpr long long kTot = 2 * kM;
constexpr int kChunk = 2048;                    // elems per scan block
constexpr int kNB1 = (kN + kChunk - 1) / kChunk; // 245
constexpr int kLdsStride = 132;                 // 528 B row pitch (16B-aligned)
// fused5 geometry: 16-row segments, one wave per run of 8 segments
constexpr int kSegRows = 16;
constexpr int kSegFloats = kSegRows * kD;       // 2048 floats = 8 wave-float4-loads
constexpr int kSegs = (int)(kTot / kSegFloats); // 62500
constexpr int kSegsB1 = kSegs / 2;              // 31250 (bank boundary, exact)
constexpr int kSPW = 8;                         // segments per wave
constexpr int kWaves5 = (kSegs + kSPW - 1) / kSPW;   // 7813
constexpr int kBlocks5 = (kWaves5 + 3) / 4;          // 1954
}

// ---------- CSR setup: bucket pairs by row index ----------

__global__ __launch_bounds__(256) void zero2_kernel(int* __restrict__ A, int* __restrict__ cur)
{
    int i = blockIdx.x * 256 + threadIdx.x;
    if (i < kN) { A[i] = 0; cur[i] = 0; }
}

__global__ __launch_bounds__(256) void hist_kernel(const int* __restrict__ cidx, int* __restrict__ A)
{
    int i = blockIdx.x * 256 + threadIdx.x;
    if (i < kNPair) atomicAdd(&A[cidx[i]], 1);
}

__global__ __launch_bounds__(256) void scan1_kernel(const int* __restrict__ A, int* __restrict__ bsum)
{
    long long base = (long long)blockIdx.x * kChunk;
    int t = threadIdx.x;
    int s = 0;
    #pragma unroll
    for (int j = 0; j < 8; ++j) {
        long long i = base + t * 8 + j;
        if (i < kN) s += A[i];
    }
    __shared__ int lds[256];
    lds[t] = s; __syncthreads();
    for (int st = 128; st > 0; st >>= 1) {
        if (t < st) lds[t] += lds[t + st];
        __syncthreads();
    }
    if (t == 0) bsum[blockIdx.x] = lds[0];
}

__global__ __launch_bounds__(256) void scan2_kernel(
    const int* __restrict__ bsum, int* __restrict__ bpre, int* __restrict__ offs)
{
    int t = threadIdx.x;
    int v = (t < kNB1) ? bsum[t] : 0;
    __shared__ int lds[256];
    lds[t] = v; __syncthreads();
    for (int st = 1; st < 256; st <<= 1) {
        int add = (t >= st) ? lds[t - st] : 0;
        __syncthreads();
        lds[t] += add;
        __syncthreads();
    }
    if (t < kNB1) bpre[t] = lds[t] - v;       // exclusive
    if (t == kNB1 - 1) offs[kN] = lds[t];     // total = kNPair
}

__global__ __launch_bounds__(256) void scan3_kernel(
    const int* __restrict__ A, const int* __restrict__ bpre, int* __restrict__ offs)
{
    int t = threadIdx.x;
    long long base = (long long)blockIdx.x * kChunk;
    int c[8]; int s = 0;
    #pragma unroll
    for (int j = 0; j < 8; ++j) {
        long long i = base + t * 8 + j;
        c[j] = (i < kN) ? A[i] : 0;
        s += c[j];
    }
    __shared__ int lds[256];
    lds[t] = s; __syncthreads();
    for (int st = 1; st < 256; st <<= 1) {
        int add = (t >= st) ? lds[t - st] : 0;
        __syncthreads();
        lds[t] += add;
        __syncthreads();
    }
    int excl = lds[t] - s + bpre[blockIdx.x];
    #pragma unroll
    for (int j = 0; j < 8; ++j) {
        long long i = base + t * 8 + j;
        if (i < kN) { offs[i] = excl; excl += c[j]; }
    }
}

__global__ __launch_bounds__(256) void scatter_kernel(
    const int* __restrict__ cidx, const int* __restrict__ offs,
    int* __restrict__ cur, int* __restrict__ sorted)
{
    int p = blockIdx.x * 256 + threadIdx.x;
    if (p < kNPair) {
        int r = cidx[p];
        int pos = offs[r] + atomicAdd(&cur[r], 1);
        sorted[pos] = p;   // bucket order nondeterministic; e values are not
    }
}

// ---------- fused v5: wave-autonomous streaming, ZERO barriers ----------
// Each wave owns 8 consecutive 16-row segments and a private LDS slice.
// Per segment: issue next segment's 8 float4 HBM loads; stage current segment
// to LDS + shifted aligned float4 output stores (carry register persists);
// then dot this segment's pairs one-per-lane from own LDS against L2-resident
// teacher/student. No __syncthreads -> prefetched loads stay in flight
// (in-order vmcnt retirement), HBM stays saturated through the dot phase.
__global__ __launch_bounds__(256) void fused5_kernel(
    const float* __restrict__ mem1, const float* __restrict__ mem2,
    const float* __restrict__ teacher, const float* __restrict__ student,
    const int* __restrict__ offs, const int* __restrict__ sorted,
    const int* __restrict__ cidx,
    float* __restrict__ out, float* __restrict__ e2, float* __restrict__ e1)
{
    __shared__ float tile[4][kSegRows * kLdsStride];
    const int tid = threadIdx.x;
    const int lane = tid & 63;
    const int w = tid >> 6;
    float* my = tile[w];

    long long gw = (long long)blockIdx.x * 4 + w;
    long long s0 = gw * kSPW;
    if (s0 >= kSegs) return;
    long long s1 = s0 + kSPW; if (s1 > kSegs) s1 = kSegs;

    float4* ov = reinterpret_cast<float4*>(out);
    const float4* m1v = reinterpret_cast<const float4*>(mem1);
    const float4* m2v = reinterpret_cast<const float4*>(mem2);

    if (gw == 0 && lane == 0) out[kTot] = mem2[kM - 1];   // final tail element

    // carry = S[s0*2048 - 1]
    float carry = 0.f;
    if (s0 > 0) {
        long long g = s0 * kSegFloats - 1;
        carry = (g < kM) ? mem1[g] : mem2[g - kM];
    }

    // prologue: load segment s0
    float4 va[8];
    {
        bool b1 = (s0 < kSegsB1);
        long long lb4 = (b1 ? s0 : s0 - kSegsB1) * 8 * 64;
        const float4* bp = b1 ? m1v : m2v;
        #pragma unroll
        for (int i = 0; i < 8; ++i) va[i] = bp[lb4 + i * 64 + lane];
    }

    for (long long s = s0; s < s1; ++s) {
        // prefetch next segment
        float4 vb[8];
        if (s + 1 < s1) {
            bool nb1 = (s + 1 < kSegsB1);
            long long lb4 = (nb1 ? (s + 1) : (s + 1 - kSegsB1)) * 8 * 64;
            const float4* bp = nb1 ? m1v : m2v;
            #pragma unroll
            for (int i = 0; i < 8; ++i) vb[i] = bp[lb4 + i * 64 + lane];
        }

        // stage to LDS + shifted aligned output stores
        long long j0 = s * 8;
        #pragma unroll
        for (int i = 0; i < 8; ++i) {
            float4 cur = va[i];
            int lr = i * 2 + (lane >> 5);
            *reinterpret_cast<float4*>(&my[lr * kLdsStride + (lane & 31) * 4]) = cur;
            float pw = __shfl_up(cur.w, 1);
            if (lane == 0) pw = carry;
            carry = __shfl(cur.w, 63);
            long long k4 = (j0 + i) * 64 + lane;
            if (k4 != 0) {
                ov[k4] = make_float4(pw, cur.x, cur.y, cur.z);
            } else {
                out[1] = cur.x; out[2] = cur.y; out[3] = cur.z;
            }
        }

        // dots for this segment's pairs, one per lane, from own LDS
        bool b1 = (s < kSegsB1);
        int r0 = (int)((b1 ? s : s - kSegsB1) * kSegRows);
        int o0  = offs[r0];
        int cnt = offs[r0 + kSegRows] - o0;
        const float* emb = b1 ? teacher : student;   // bank1 -> e2, bank2 -> e1
        float* ep = b1 ? e2 : e1;
        for (int t = lane; t < cnt; t += 64) {
            int p  = sorted[o0 + t];
            int lr = cidx[p] - r0;
            unsigned bb = (unsigned)p / (unsigned)kKC;
            const float4* er = reinterpret_cast<const float4*>(emb + (long long)bb * kD);
            const float* row = &my[lr * kLdsStride];
            float ax = 0.f, ay = 0.f, az = 0.f, aw = 0.f;
            #pragma unroll 8
            for (int kk = 0; kk < 32; ++kk) {
                float4 rv = *reinterpret_cast<const float4*>(&row[kk * 4]);
                float4 ev = er[kk];
                ax += rv.x * ev.x; ay += rv.y * ev.y;
                az += rv.z * ev.z; aw += rv.w * ev.w;
            }
            ep[p] = __expf((ax + ay + az + aw) * kTInv);
        }

        #pragma unroll
        for (int i = 0; i < 8; ++i) va[i] = vb[i];
    }
}

// ---------- fallback path (R2): separate gather + copy ----------

__global__ __launch_bounds__(256) void dots_kernel(
    const float* __restrict__ mem1, const float* __restrict__ mem2,
    const float* __restrict__ teacher, const float* __restrict__ student,
    const int* __restrict__ cidx,
    float* __restrict__ e2, float* __restrict__ e1)
{
    int gtid = blockIdx.x * 256 + threadIdx.x;
    int wave = gtid >> 6;
    int lane = threadIdx.x & 63;
    if (wave >= kNPair) return;
    int b = wave / kKC;
    long long row = (long long)cidx[wave] * kD;
    const float2 m1 = *reinterpret_cast<const float2*>(mem1 + row + lane * 2);
    const float2 m2 = *reinterpret_cast<const float2*>(mem2 + row + lane * 2);
    const float2 tv = *reinterpret_cast<const float2*>(teacher + b * kD + lane * 2);
    const float2 sv = *reinterpret_cast<const float2*>(student + b * kD + lane * 2);
    float d1 = m1.x * tv.x + m1.y * tv.y;
    float d2 = m2.x * sv.x + m2.y * sv.y;
    #pragma unroll
    for (int off = 32; off > 0; off >>= 1) {
        d1 += __shfl_xor(d1, off);
        d2 += __shfl_xor(d2, off);
    }
    if (lane == 0) {
        e2[wave] = __expf(d1 * kTInv);
        e1[wave] = __expf(d2 * kTInv);
    }
}

__global__ __launch_bounds__(256) void copy_kernel(
    const float* __restrict__ mem1, const float* __restrict__ mem2,
    float* __restrict__ out)
{
    const long long NV4 = (kTot + 1) / 4;
    const long long KS  = kM / 4;
    const float4* m1v = reinterpret_cast<const float4*>(mem1);
    const float4* m2v = reinterpret_cast<const float4*>(mem2);
    float4* ov = reinterpret_cast<float4*>(out);
    long long stride = (long long)gridDim.x * 256;
    for (long long k = (long long)blockIdx.x * 256 + threadIdx.x; k < NV4; k += stride) {
        if (k == 0) {
            out[1] = mem1[0]; out[2] = mem1[1]; out[3] = mem1[2];
            out[kTot] = mem2[kM - 1];
            continue;
        }
        float4 r;
        if (k < KS) {
            float4 a = m1v[k - 1];
            float4 b = m1v[k];
            r = make_float4(a.w, b.x, b.y, b.z);
        } else if (k == KS) {
            r = make_float4(mem1[kM - 1], mem2[0], mem2[1], mem2[2]);
        } else {
            float4 a = m2v[k - KS - 1];
            float4 b = m2v[k - KS];
            r = make_float4(a.w, b.x, b.y, b.z);
        }
        ov[k] = r;
    }
}

// ---------- loss chain ----------

__global__ __launch_bounds__(256) void sums_kernel(
    const float* __restrict__ e2, const float* __restrict__ e1,
    float* __restrict__ p2, float* __restrict__ p1)
{
    __shared__ float s2[256], s1[256];
    float a2 = 0.f, a1 = 0.f;
    for (int i = blockIdx.x * 256 + threadIdx.x; i < kNPair; i += 256 * kRB) {
        a2 += e2[i];
        a1 += e1[i];
    }
    s2[threadIdx.x] = a2; s1[threadIdx.x] = a1;
    __syncthreads();
    for (int st = 128; st > 0; st >>= 1) {
        if ((int)threadIdx.x < st) {
            s2[threadIdx.x] += s2[threadIdx.x + st];
            s1[threadIdx.x] += s1[threadIdx.x + st];
        }
        __syncthreads();
    }
    if (threadIdx.x == 0) { p2[blockIdx.x] = s2[0]; p1[blockIdx.x] = s1[0]; }
}

__global__ __launch_bounds__(256) void z_kernel(
    const float* __restrict__ p2, const float* __restrict__ p1, float* __restrict__ z)
{
    __shared__ float s2[256], s1[256];
    s2[threadIdx.x] = p2[threadIdx.x];
    s1[threadIdx.x] = p1[threadIdx.x];
    __syncthreads();
    for (int st = 128; st > 0; st >>= 1) {
        if ((int)threadIdx.x < st) {
            s2[threadIdx.x] += s2[threadIdx.x + st];
            s1[threadIdx.x] += s1[threadIdx.x + st];
        }
        __syncthreads();
    }
    if (threadIdx.x == 0) {
        const float scale = (float)kN / (float)kNPair;
        z[0] = s2[0] * scale;
        z[1] = s1[0] * scale;
    }
}

__global__ __launch_bounds__(256) void lossp_kernel(
    const float* __restrict__ e2, const float* __restrict__ e1,
    const float* __restrict__ z, float* __restrict__ lp)
{
    const float mpn = 2048.0f / 500000.0f;
    const float noise = mpn + 1e-7f;
    const float iz2 = 1.0f / z[0];
    const float iz1 = 1.0f / z[1];
    float acc = 0.f;
    for (int i = blockIdx.x * 256 + threadIdx.x; i < kNPair; i += 256 * kRB) {
        int k = i % kKC;
        float x2 = e2[i] * iz2;
        float x1 = e1[i] * iz1;
        if (k == 0) {
            acc += __logf(x2 / (x2 + noise)) + __logf(x1 / (x1 + noise));
        } else {
            acc += __logf(mpn / (x2 + noise)) + __logf(mpn / (x1 + noise));
        }
    }
    __shared__ float s[256];
    s[threadIdx.x] = acc;
    __syncthreads();
    for (int st = 128; st > 0; st >>= 1) {
        if ((int)threadIdx.x < st) s[threadIdx.x] += s[threadIdx.x + st];
        __syncthreads();
    }
    if (threadIdx.x == 0) lp[blockIdx.x] = s[0];
}

__global__ __launch_bounds__(256) void final_kernel(
    const float* __restrict__ lp, float* __restrict__ out)
{
    __shared__ float s[256];
    s[threadIdx.x] = lp[threadIdx.x];
    __syncthreads();
    for (int st = 128; st > 0; st >>= 1) {
        if ((int)threadIdx.x < st) s[threadIdx.x] += s[threadIdx.x + st];
        __syncthreads();
    }
    if (threadIdx.x == 0) out[0] = -s[0] / (float)kB;
}

// ---------- momentum update of the 256 pos rows ----------

__global__ __launch_bounds__(64) void update_kernel(
    const float* __restrict__ mem1, const float* __restrict__ mem2,
    const float* __restrict__ student, const float* __restrict__ teacher,
    const int* __restrict__ pos_idx,
    float* __restrict__ out1, float* __restrict__ out2)
{
    int b = blockIdx.x;
    int lane = threadIdx.x;
    int p = pos_idx[b];
    for (int b2 = b + 1; b2 < kB; ++b2)
        if (pos_idx[b2] == p) return;   // a later write wins
    long long row = (long long)p * kD;
    float2 m1 = *reinterpret_cast<const float2*>(mem1 + row + lane * 2);
    float2 m2 = *reinterpret_cast<const float2*>(mem2 + row + lane * 2);
    float2 sv = *reinterpret_cast<const float2*>(student + b * kD + lane * 2);
    float2 tv = *reinterpret_cast<const float2*>(teacher + b * kD + lane * 2);
    float2 l1 = make_float2(m1.x * kMom + sv.x * (1.f - kMom),
                            m1.y * kMom + sv.y * (1.f - kMom));
    float2 l2 = make_float2(m2.x * kMom + tv.x * (1.f - kMom),
                            m2.y * kMom + tv.y * (1.f - kMom));
    float n1 = l1.x * l1.x + l1.y * l1.y;
    float n2 = l2.x * l2.x + l2.y * l2.y;
    #pragma unroll
    for (int off = 32; off > 0; off >>= 1) {
        n1 += __shfl_xor(n1, off);
        n2 += __shfl_xor(n2, off);
    }
    float i1 = 1.0f / sqrtf(n1);
    float i2 = 1.0f / sqrtf(n2);
    out1[row + lane * 2]     = l1.x * i1;
    out1[row + lane * 2 + 1] = l1.y * i1;
    out2[row + lane * 2]     = l2.x * i2;
    out2[row + lane * 2 + 1] = l2.y * i2;
}

extern "C" void kernel_launch(void* const* d_in, const int* in_sizes, int n_in,
                              void* d_out, int out_size, void* d_ws, size_t ws_size,
                              hipStream_t stream) {
    const float* student = (const float*)d_in[0];
    const float* teacher = (const float*)d_in[1];
    const float* mem1    = (const float*)d_in[2];
    const float* mem2    = (const float*)d_in[3];
    const int*   pos_idx = (const int*)d_in[4];
    const int*   cidx    = (const int*)d_in[5];

    float* out  = (float*)d_out;
    float* out1 = out + 1;
    float* out2 = out + 1 + kM;

    // ws layout
    float* ws = (float*)d_ws;
    float* e2 = ws;                         // kNPair
    float* e1 = e2 + kNPair;                // kNPair
    float* p2 = e1 + kNPair;                // kRB
    float* p1 = p2 + kRB;                   // kRB
    float* zz = p1 + kRB;                   // 2
    float* lp = zz + 2;                     // kRB
    int*   A      = (int*)(lp + kRB);       // kN   (counts)
    int*   cur    = A + kN;                 // kN   (scatter cursor)
    int*   offs   = cur + kN;               // kN + 1
    int*   bsum   = offs + kN + 1;          // kNB1
    int*   bpre   = bsum + kNB1;            // kNB1
    int*   sorted = bpre + kNB1;            // kNPair
    size_t need = (size_t)((char*)(sorted + kNPair) - (char*)d_ws);

    if (ws_size >= need) {
        // CSR setup
        zero2_kernel<<<(kN + 255) / 256, 256, 0, stream>>>(A, cur);
        hist_kernel<<<(kNPair + 255) / 256, 256, 0, stream>>>(cidx, A);
        scan1_kernel<<<kNB1, 256, 0, stream>>>(A, bsum);
        scan2_kernel<<<1, 256, 0, stream>>>(bsum, bpre, offs);
        scan3_kernel<<<kNB1, 256, 0, stream>>>(A, bpre, offs);
        scatter_kernel<<<(kNPair + 255) / 256, 256, 0, stream>>>(cidx, offs, cur, sorted);
        // fused barrier-free streaming copy + dots
        fused5_kernel<<<kBlocks5, 256, 0, stream>>>(mem1, mem2, teacher, student,
                                                    offs, sorted, cidx, out, e2, e1);
    } else {
        // fallback: R2 path
        int nblocks = (kNPair + 3) / 4;
        dots_kernel<<<nblocks, 256, 0, stream>>>(mem1, mem2, teacher, student, cidx, e2, e1);
        copy_kernel<<<2048, 256, 0, stream>>>(mem1, mem2, out);
    }

    sums_kernel<<<kRB, 256, 0, stream>>>(e2, e1, p2, p1);
    z_kernel<<<1, 256, 0, stream>>>(p2, p1, zz);
    lossp_kernel<<<kRB, 256, 0, stream>>>(e2, e1, zz, lp);
    final_kernel<<<1, 256, 0, stream>>>(lp, out);
    update_kernel<<<kB, 64, 0, stream>>>(mem1, mem2, student, teacher, pos_idx, out1, out2);
}